// Round 7
// baseline (101.676 us; speedup 1.0000x reference)
//
#include <hip/hip_runtime.h>
#include <math.h>

#define M 1920        // K*N rows
#define DIMS 512
#define KGRP 128
#define NGRP 15
#define NQ 32         // quads of 4 groups
#define KC 32         // k-chunk = one MFMA K-step
#define NTILES 528    // NQ*(NQ+1)/2
#define SPAD 40       // staging row stride in shorts: 80 B, uniform bank spread, 16B-aligned

typedef __attribute__((ext_vector_type(8))) short short8;
typedef __attribute__((ext_vector_type(4))) short short4v;
typedef __attribute__((ext_vector_type(4))) float f32x4;

#define MFMA(A, B, C) __builtin_amdgcn_mfma_f32_16x16x32_bf16(A, B, C, 0, 0, 0)

// exact split: x = hi + lo + eps, |eps| <= ~2^-16 |x|
__device__ inline void split2(float x, short& h, short& l) {
    unsigned u = __float_as_uint(x);
    h = (short)(u >> 16);                              // truncated bf16
    float fl = x - __uint_as_float(u & 0xFFFF0000u);   // exact residual
    l = (short)(__float_as_uint(fl) >> 16);
}

// ---- fused per-group kernel: stage+split -> Ehi/Elo, dAA, sqn, centroid, radius ----
__global__ __launch_bounds__(256) void group_kernel(const float* __restrict__ E,
                                                    float* __restrict__ dAAg,
                                                    float* __restrict__ sqn,
                                                    float* __restrict__ md,
                                                    short* __restrict__ Ehi,
                                                    short* __restrict__ Elo,
                                                    float* __restrict__ acc,
                                                    unsigned* __restrict__ cnt) {
    const int a = blockIdx.x;
    const int t = threadIdx.x;
    __shared__ float Ash[NGRP][516];
    __shared__ float cent[DIMS];
    __shared__ float mdp[NGRP];

    // stage group into LDS + write hi/lo bf16 split to global
    const float4* Ea = reinterpret_cast<const float4*>(E + (size_t)a * NGRP * DIMS);
    for (int e = t; e < NGRP * 128; e += 256) {
        int r = e >> 7, c4 = e & 127;
        float4 v = Ea[r * 128 + c4];
        *reinterpret_cast<float4*>(&Ash[r][c4 * 4]) = v;
        float x[4] = {v.x, v.y, v.z, v.w};
        short4v h, l;
        #pragma unroll
        for (int i = 0; i < 4; ++i) { short hh, ll; split2(x[i], hh, ll); h[i] = hh; l[i] = ll; }
        size_t go = (size_t)(a * NGRP + r) * DIMS + c4 * 4;
        *reinterpret_cast<short4v*>(&Ehi[go]) = h;
        *reinterpret_cast<short4v*>(&Elo[go]) = l;
    }
    __syncthreads();

    // dAA pairs (waves 0-1), sqn (wave 2 lanes 0-14), diag zeros (wave 3 lanes 0-14)
    if (t < 105) {
        int i = 0, r2 = t;
        while (r2 >= 14 - i) { r2 -= 14 - i; ++i; }
        int j = i + 1 + r2;
        float s = 0.0f;
        #pragma unroll 4
        for (int k = 0; k < DIMS; k += 4) {
            float4 ai = *reinterpret_cast<const float4*>(&Ash[i][k]);
            float4 aj = *reinterpret_cast<const float4*>(&Ash[j][k]);
            float dx = ai.x - aj.x, dy = ai.y - aj.y, dz = ai.z - aj.z, dw = ai.w - aj.w;
            s = fmaf(dx, dx, s); s = fmaf(dy, dy, s);
            s = fmaf(dz, dz, s); s = fmaf(dw, dw, s);
        }
        float d = sqrtf(s);
        dAAg[a * 225 + i * 15 + j] = d;
        dAAg[a * 225 + j * 15 + i] = d;
    } else if (t >= 128 && t < 128 + NGRP) {
        int m = t - 128;
        float s = 0.0f;
        #pragma unroll 4
        for (int k = 0; k < DIMS; k += 4) {
            float4 ai = *reinterpret_cast<const float4*>(&Ash[m][k]);
            s = fmaf(ai.x, ai.x, s); s = fmaf(ai.y, ai.y, s);
            s = fmaf(ai.z, ai.z, s); s = fmaf(ai.w, ai.w, s);
        }
        sqn[a * NGRP + m] = s;
    } else if (t >= 192 && t < 192 + NGRP) {
        dAAg[a * 225 + (t - 192) * 16] = 0.0f;
    }
    // centroid on waves 2-3 (4 dims per thread)
    if (t >= 128) {
        int d0 = (t - 128) * 4;
        float sx = 0.f, sy = 0.f, sz = 0.f, sw = 0.f;
        #pragma unroll
        for (int m = 0; m < NGRP; ++m) {
            float4 v = *reinterpret_cast<const float4*>(&Ash[m][d0]);
            sx += v.x; sy += v.y; sz += v.z; sw += v.w;
        }
        float4 c = {sx / (float)NGRP, sy / (float)NGRP, sz / (float)NGRP, sw / (float)NGRP};
        *reinterpret_cast<float4*>(&cent[d0]) = c;
    }
    __syncthreads();

    // radius: 15 rows x 16 lanes, strided dims
    if (t < 240) {
        int m = t >> 4, l16 = t & 15;
        float s = 0.0f;
        #pragma unroll
        for (int it = 0; it < 8; ++it) {
            int d = it * 64 + l16 * 4;
            float4 v = *reinterpret_cast<const float4*>(&Ash[m][d]);
            float4 c = *reinterpret_cast<const float4*>(&cent[d]);
            float dx = v.x - c.x, dy = v.y - c.y, dz = v.z - c.z, dw = v.w - c.w;
            s = fmaf(dx, dx, s); s = fmaf(dy, dy, s);
            s = fmaf(dz, dz, s); s = fmaf(dw, dw, s);
        }
        s += __shfl_xor(s, 1); s += __shfl_xor(s, 2);
        s += __shfl_xor(s, 4); s += __shfl_xor(s, 8);
        if (l16 == 0) mdp[m] = (s > 0.0f) ? sqrtf(s) : 0.0f;
    }
    __syncthreads();
    if (t == 0) {
        float su = 0.0f;
        #pragma unroll
        for (int m = 0; m < NGRP; ++m) su += mdp[m];
        md[a] = su / (float)NGRP;
    }
    if (a == 0 && t == 1) *acc = 0.0f;
    if (a == 0 && t == 2) *cnt = 0u;
}

// ---- quad tile via split-bf16 MFMA (pre-split inputs) + fused margin + last-block finalize ----
__global__ __launch_bounds__(256) void quad_kernel(const short* __restrict__ Ehi,
                                                   const short* __restrict__ Elo,
                                                   const float* __restrict__ sqn,
                                                   const float* __restrict__ dAAg,
                                                   const float* __restrict__ md,
                                                   float* __restrict__ acc,
                                                   unsigned* __restrict__ cnt,
                                                   float* __restrict__ out) {
    // decode blockIdx -> (qa, qb), qa <= qb
    int qa = 0, rem = blockIdx.x;
    while (rem >= NQ - qa) { rem -= NQ - qa; ++qa; }
    const int qb = qa + rem;

    __shared__ short Ah[2][64][SPAD], Al[2][64][SPAD], Bh[2][64][SPAD], Bl[2][64][SPAD];
    __shared__ float Dt[64][68];
    __shared__ float dAAc[4][228];
    __shared__ float sqnA[64], sqnB[64];
    __shared__ unsigned char ijt[105][2];
    __shared__ float wred[4];
    __shared__ int islast;

    const int t = threadIdx.x;
    const int row0 = qa * 60, col0 = qb * 60;

    for (int e = t; e < 900; e += 256)
        dAAc[e / 225][e % 225] = dAAg[(qa * 4 + e / 225) * 225 + e % 225];
    if (t < 64) {
        sqnA[t] = sqn[row0 + min(t, 59)];
        sqnB[t] = sqn[col0 + min(t, 59)];
    }
    if (t < 105) {
        int i = 0, r2 = t;
        while (r2 >= 14 - i) { r2 -= 14 - i; ++i; }
        ijt[t][0] = (unsigned char)i;
        ijt[t][1] = (unsigned char)(i + 1 + r2);
    }

    const int wv = t >> 6, lane = t & 63;
    const int lr = lane & 15, lk = (lane >> 4) * 8;

    // staging assignment: thread -> (row 0..63, k-octet 0/8/16/24)
    const int srow = t >> 2;
    const int skq = (t & 3) * 8;
    const size_t aoff = (size_t)(row0 + min(srow, 59)) * DIMS + skq;
    const size_t boff = (size_t)(col0 + min(srow, 59)) * DIMS + skq;

    // prologue: chunk 0 into buffer 0
    short8 rah = *reinterpret_cast<const short8*>(Ehi + aoff);
    short8 ral = *reinterpret_cast<const short8*>(Elo + aoff);
    short8 rbh = *reinterpret_cast<const short8*>(Ehi + boff);
    short8 rbl = *reinterpret_cast<const short8*>(Elo + boff);
    *reinterpret_cast<short8*>(&Ah[0][srow][skq]) = rah;
    *reinterpret_cast<short8*>(&Al[0][srow][skq]) = ral;
    *reinterpret_cast<short8*>(&Bh[0][srow][skq]) = rbh;
    *reinterpret_cast<short8*>(&Bl[0][srow][skq]) = rbl;
    __syncthreads();

    f32x4 z4 = {0.f, 0.f, 0.f, 0.f};
    f32x4 c0 = z4, c1 = z4, c2 = z4, c3 = z4;

    for (int k = 0; k < DIMS / KC; ++k) {
        const int cur = k & 1;
        if (k < DIMS / KC - 1) {
            const int off = (k + 1) * KC;
            rah = *reinterpret_cast<const short8*>(Ehi + aoff + off);
            ral = *reinterpret_cast<const short8*>(Elo + aoff + off);
            rbh = *reinterpret_cast<const short8*>(Ehi + boff + off);
            rbl = *reinterpret_cast<const short8*>(Elo + boff + off);
        }
        short8 a_h = *reinterpret_cast<const short8*>(&Ah[cur][(wv << 4) + lr][lk]);
        short8 a_l = *reinterpret_cast<const short8*>(&Al[cur][(wv << 4) + lr][lk]);
        short8 b_h0 = *reinterpret_cast<const short8*>(&Bh[cur][lr][lk]);
        short8 b_l0 = *reinterpret_cast<const short8*>(&Bl[cur][lr][lk]);
        short8 b_h1 = *reinterpret_cast<const short8*>(&Bh[cur][16 + lr][lk]);
        short8 b_l1 = *reinterpret_cast<const short8*>(&Bl[cur][16 + lr][lk]);
        short8 b_h2 = *reinterpret_cast<const short8*>(&Bh[cur][32 + lr][lk]);
        short8 b_l2 = *reinterpret_cast<const short8*>(&Bl[cur][32 + lr][lk]);
        short8 b_h3 = *reinterpret_cast<const short8*>(&Bh[cur][48 + lr][lk]);
        short8 b_l3 = *reinterpret_cast<const short8*>(&Bl[cur][48 + lr][lk]);
        c0 = MFMA(a_l, b_h0, c0); c0 = MFMA(a_h, b_l0, c0); c0 = MFMA(a_h, b_h0, c0);
        c1 = MFMA(a_l, b_h1, c1); c1 = MFMA(a_h, b_l1, c1); c1 = MFMA(a_h, b_h1, c1);
        c2 = MFMA(a_l, b_h2, c2); c2 = MFMA(a_h, b_l2, c2); c2 = MFMA(a_h, b_h2, c2);
        c3 = MFMA(a_l, b_h3, c3); c3 = MFMA(a_h, b_l3, c3); c3 = MFMA(a_h, b_h3, c3);
        if (k < DIMS / KC - 1) {
            const int nxt = cur ^ 1;
            *reinterpret_cast<short8*>(&Ah[nxt][srow][skq]) = rah;
            *reinterpret_cast<short8*>(&Al[nxt][srow][skq]) = ral;
            *reinterpret_cast<short8*>(&Bh[nxt][srow][skq]) = rbh;
            *reinterpret_cast<short8*>(&Bl[nxt][srow][skq]) = rbl;
        }
        __syncthreads();
    }

    // epilogue: C/D layout col=lane&15, row=(lane>>4)*4+reg  [m89]
    {
        const int rbase = (wv << 4) + ((lane >> 4) << 2);
        #define EPI(J, CJ)                                                    \
        {   _Pragma("unroll")                                                 \
            for (int r = 0; r < 4; ++r) {                                     \
                int rr = rbase + r;                                           \
                int cc = (J << 4) + lr;                                       \
                float sq = sqnA[rr] + sqnB[cc] - 2.0f * CJ[r];                \
                Dt[rr][cc] = sqrtf(fmaxf(sq, 0.0f));                          \
            }                                                                 \
        }
        EPI(0, c0) EPI(1, c1) EPI(2, c2) EPI(3, c3)
        #undef EPI
    }
    __syncthreads();

    // fused margin: pairs (a,b) = (qa*4+pa, qb*4+pb) with a < b
    float v = 0.0f;
    for (int it = t; it < 16 * 105; it += 256) {
        int p16 = it / 105, r2 = it % 105;
        int pa = p16 >> 2, pb = p16 & 3;
        int a = qa * 4 + pa, b = qb * 4 + pb;
        if (a < b) {
            int i = ijt[r2][0], j = ijt[r2][1];
            float base = dAAc[pa][i * 15 + j] + 1.5f;
            const float* drow = &Dt[pa * 15 + i][pb * 15];
            #pragma unroll
            for (int l = 0; l < NGRP; ++l) v += fmaxf(base - drow[l], 0.0f);
        }
    }
    #pragma unroll
    for (int off = 32; off > 0; off >>= 1) v += __shfl_down(v, off);
    if ((t & 63) == 0) wred[t >> 6] = v;
    __syncthreads();
    if (t == 0) {
        atomicAdd(acc, wred[0] + wred[1] + wred[2] + wred[3]);
        __threadfence();
        unsigned tk = atomicAdd(cnt, 1u);
        islast = (tk == NTILES - 1) ? 1 : 0;
    }
    __syncthreads();

    // last block finalizes (md written by previous dispatch; acc read via atomic)
    if (islast && t < 128) {
        __shared__ float w2[2];
        __shared__ float tr_s;
        __threadfence();
        float mv = md[t];
        float s = mv;
        #pragma unroll
        for (int off = 32; off > 0; off >>= 1) s += __shfl_down(s, off);
        if ((t & 63) == 0) w2[t >> 6] = s;
        __syncthreads();
        if (t == 0) tr_s = (w2[0] + w2[1]) / 128.0f;
        __syncthreads();
        const float tr = tr_s;
        float dev = fabsf(mv / tr - 1.0f);
        #pragma unroll
        for (int off = 32; off > 0; off >>= 1) dev += __shfl_down(dev, off);
        if ((t & 63) == 0) w2[t >> 6] = dev;
        __syncthreads();
        if (t == 0) {
            float total = atomicAdd(acc, 0.0f);   // coherent device-scope read
            float penalty = 0.05f * ((w2[0] + w2[1]) / 128.0f);
            float sml = total / 1575.0f / 8128.0f;   // /(N*N*(N-1)/2)/total_pairs
            out[0] = sml + penalty;
        }
    }
}

extern "C" void kernel_launch(void* const* d_in, const int* in_sizes, int n_in,
                              void* d_out, int out_size, void* d_ws, size_t ws_size,
                              hipStream_t stream) {
    const float* E = (const float*)d_in[0];
    float* out = (float*)d_out;
    char* ws = (char*)d_ws;
    float* acc    = (float*)(ws);              // 1 float
    unsigned* cnt = (unsigned*)(ws + 64);      // 1 uint ticket counter
    float* sqn    = (float*)(ws + 256);        // 1920 floats
    float* dAAg   = (float*)(ws + 8192);       // 128*225 floats
    float* md     = (float*)(ws + 123648);     // 128 floats
    short* Ehi    = (short*)(ws + 131072);     // 1920*512 shorts = 1.97 MB
    short* Elo    = (short*)(ws + 2097152);    // 1920*512 shorts
    // total ws use ~4.1 MB

    group_kernel<<<KGRP, 256, 0, stream>>>(E, dAAg, sqn, md, Ehi, Elo, acc, cnt);
    quad_kernel<<<NTILES, 256, 0, stream>>>(Ehi, Elo, sqn, dAAg, md, acc, cnt, out);
}